// Round 14
// baseline (4957.860 us; speedup 1.0000x reference)
//
#include <hip/hip_runtime.h>
#include <hip/hip_bf16.h>
#include <math.h>

#define NN   100000
#define FIN  512
#define HH   256
#define FOUT 64

typedef __attribute__((ext_vector_type(8))) short s16x8;
typedef __attribute__((ext_vector_type(4))) short s16x4;
typedef __attribute__((ext_vector_type(4))) float f32x4;

// ---------------- CSR build ----------------
__global__ void k_count(const int* __restrict__ dst, int* __restrict__ cnt, int E) {
    int i = blockIdx.x * 256 + threadIdx.x;
    if (i < E) atomicAdd(&cnt[dst[i]], 1);
}

__global__ void k_block_sums(const int* __restrict__ cnt, int* __restrict__ partial, int n) {
    __shared__ int red[256];
    int base = blockIdx.x * 1024;
    int t = threadIdx.x;
    int s = 0;
#pragma unroll
    for (int i = 0; i < 4; i++) { int idx = base + t * 4 + i; if (idx < n) s += cnt[idx]; }
    red[t] = s; __syncthreads();
    for (int off = 128; off > 0; off >>= 1) {
        if (t < off) red[t] += red[t + off];
        __syncthreads();
    }
    if (t == 0) partial[blockIdx.x] = red[0];
}

__global__ void k_scan_partials(int* partial, int nb, int* row_ptr, int n) {
    if (threadIdx.x == 0) {
        int run = 0;
        for (int i = 0; i < nb; i++) { int v = partial[i]; partial[i] = run; run += v; }
        row_ptr[n] = run;
    }
}

// also computes dinv (fused, saves a launch)
__global__ void k_write_rowptr(const int* __restrict__ cnt, const int* __restrict__ partial,
                               int* __restrict__ row_ptr, int* __restrict__ cur,
                               float* __restrict__ dinv, int n) {
    __shared__ int sc[256];
    int base = blockIdx.x * 1024;
    int t = threadIdx.x;
    int v[4]; int s = 0;
#pragma unroll
    for (int i = 0; i < 4; i++) { int idx = base + t * 4 + i; v[i] = (idx < n) ? cnt[idx] : 0; s += v[i]; }
    sc[t] = s; __syncthreads();
    for (int off = 1; off < 256; off <<= 1) {
        int add = (t >= off) ? sc[t - off] : 0;
        __syncthreads();
        sc[t] += add;
        __syncthreads();
    }
    int run = partial[blockIdx.x] + sc[t] - s;
#pragma unroll
    for (int i = 0; i < 4; i++) {
        int idx = base + t * 4 + i;
        if (idx < n) {
            row_ptr[idx] = run; cur[idx] = run; run += v[i];
            dinv[idx] = 1.0f / sqrtf((float)(v[i] + 1));
        }
    }
}

__global__ void k_scatter(const int* __restrict__ src, const int* __restrict__ dst,
                          const float* __restrict__ dinv, int* __restrict__ cur,
                          int* __restrict__ src_sorted, float* __restrict__ norm_sorted, int E) {
    int i = blockIdx.x * 256 + threadIdx.x;
    if (i < E) {
        int s = src[i], d = dst[i];
        int p = atomicAdd(&cur[d], 1);
        src_sorted[p] = s;
        norm_sorted[p] = dinv[s] * dinv[d];
    }
}

// ---------------- bf16 split helpers ----------------
__device__ __forceinline__ short f2bf_rn(float f) {
    unsigned b = __float_as_uint(f);
    unsigned r = b + 0x7FFFu + ((b >> 16) & 1u);
    return (short)(r >> 16);
}
__device__ __forceinline__ float bf2f(short h) {
    return __uint_as_float(((unsigned)(unsigned short)h) << 16);
}
__device__ __forceinline__ void split_bf16(float f, short& hi, short& lo) {
    hi = f2bf_rn(f);
    lo = f2bf_rn(f - bf2f(hi));
}

// ---------------- weight prep: W0 (scale=1, no diag) ----------------
__global__ void k_wprep(const float* __restrict__ W, short* __restrict__ whi,
                        short* __restrict__ wlo, int K) {
    int t = blockIdx.x * 256 + threadIdx.x;
    int total = K * HH / 8;
    if (t >= total) return;
    int colin = t & 15, g = (t >> 4) & 3, nt = (t >> 6) & 15, kt = t >> 10;
    int col = nt * 16 + colin, kb = kt * 32 + g * 8;
    s16x8 h8, l8;
#pragma unroll
    for (int j = 0; j < 8; j++) {
        float f = W[(size_t)(kb + j) * HH + col];
        short h, l; split_bf16(f, h, l);
        h8[j] = h; l8[j] = l;
    }
    *(s16x8*)&whi[(size_t)t * 8] = h8;
    *(s16x8*)&wlo[(size_t)t * 8] = l8;
}

// ---------------- batched weight prep for all layers: W' = beta*Ws + (1-beta)*I ----------------
__global__ void k_wprep_all(const float* __restrict__ Ws, short* __restrict__ whi,
                            short* __restrict__ wlo, int L) {
    int t = blockIdx.x * 256 + threadIdx.x;
    const int per = HH * HH / 8;
    if (t >= L * per) return;
    int layer = t / per;
    int tl = t - layer * per;
    float beta = (float)log(0.5 / (layer + 1) + 1.0);
    const float* W = Ws + (size_t)layer * HH * HH;
    int colin = tl & 15, g = (tl >> 4) & 3, nt = (tl >> 6) & 15, kt = tl >> 10;
    int col = nt * 16 + colin, kb = kt * 32 + g * 8;
    s16x8 h8, l8;
#pragma unroll
    for (int j = 0; j < 8; j++) {
        float f = beta * W[(size_t)(kb + j) * HH + col];
        if ((kb + j) == col) f += 1.0f - beta;
        short h, l; split_bf16(f, h, l);
        h8[j] = h; l8[j] = l;
    }
    *(s16x8*)&whi[(size_t)t * 8] = h8;
    *(s16x8*)&wlo[(size_t)t * 8] = l8;
}

// ---------------- first GEMM: X0 = relu(x@W0 + b0), 8-wave blocks, chunked out ----------------
__global__ __launch_bounds__(512, 4) void k_gemm0(
    const float* __restrict__ A, const short* __restrict__ Whi, const short* __restrict__ Wlo,
    const float* __restrict__ bias, float* __restrict__ C, int M) {
    __shared__ short As_hi[2][2048];
    __shared__ short As_lo[2][2048];
    int tid = threadIdx.x, lane = tid & 63, wid = tid >> 6;
    int wm = wid >> 2, wn = wid & 3;
    int bm = blockIdx.x * 64;
    int st_row = tid >> 2, st_g = tid & 3;
    int st_cphys = ((st_row & 15) ^ ((st_g & 1) << 2)) + 16 * st_g + 64 * (st_row >> 4);
    const float* st_ap = A + (size_t)(bm + st_row) * FIN + st_g * 8;
    bool st_ok = (tid < 256) && (bm + st_row) < M;
    int fr_g = lane >> 4, fr_r = lane & 15;
    int fr_base = (fr_r ^ ((fr_g & 1) << 2)) + 16 * fr_g;
    int c0 = (fr_base + 64 * (wm * 2 + 0)) * 8;
    int c1 = (fr_base + 64 * (wm * 2 + 1)) * 8;
    int lane_off = fr_g * 16 + fr_r;
    f32x4 acc[2][4] = {};
    f32x4 v0 = {0.f, 0.f, 0.f, 0.f}, v1 = v0, n0 = v0, n1 = v0;
    if (st_ok) { v0 = *(const f32x4*)(st_ap); v1 = *(const f32x4*)(st_ap + 4); }
    for (int kt = 0; kt < FIN / 32; kt++) {
        int buf = kt & 1;
        if (tid < 256) {
            s16x8 h8, l8;
            float fv[8] = {v0.x, v0.y, v0.z, v0.w, v1.x, v1.y, v1.z, v1.w};
#pragma unroll
            for (int j = 0; j < 8; j++) { short hh, ll; split_bf16(fv[j], hh, ll); h8[j] = hh; l8[j] = ll; }
            *(s16x8*)&As_hi[buf][st_cphys * 8] = h8;
            *(s16x8*)&As_lo[buf][st_cphys * 8] = l8;
            if (kt + 1 < FIN / 32 && st_ok) {
                int k0n = (kt + 1) * 32;
                n0 = *(const f32x4*)(st_ap + k0n);
                n1 = *(const f32x4*)(st_ap + k0n + 4);
            }
        }
        __syncthreads();
        s16x8 ah0 = *(const s16x8*)&As_hi[buf][c0], al0 = *(const s16x8*)&As_lo[buf][c0];
        s16x8 ah1 = *(const s16x8*)&As_hi[buf][c1], al1 = *(const s16x8*)&As_lo[buf][c1];
        size_t btile = (size_t)kt * 1024 + (size_t)(wn * 4) * 64;
#pragma unroll
        for (int ct = 0; ct < 4; ct++) {
            s16x8 bh = *(const s16x8*)&Whi[(btile + ct * 64 + lane_off) * 8];
            s16x8 bl = *(const s16x8*)&Wlo[(btile + ct * 64 + lane_off) * 8];
            acc[0][ct] = __builtin_amdgcn_mfma_f32_16x16x32_bf16(ah0, bh, acc[0][ct], 0, 0, 0);
            acc[0][ct] = __builtin_amdgcn_mfma_f32_16x16x32_bf16(al0, bh, acc[0][ct], 0, 0, 0);
            acc[0][ct] = __builtin_amdgcn_mfma_f32_16x16x32_bf16(ah0, bl, acc[0][ct], 0, 0, 0);
            acc[1][ct] = __builtin_amdgcn_mfma_f32_16x16x32_bf16(ah1, bh, acc[1][ct], 0, 0, 0);
            acc[1][ct] = __builtin_amdgcn_mfma_f32_16x16x32_bf16(al1, bh, acc[1][ct], 0, 0, 0);
            acc[1][ct] = __builtin_amdgcn_mfma_f32_16x16x32_bf16(ah1, bl, acc[1][ct], 0, 0, 0);
        }
        v0 = n0; v1 = n1;
        if (kt + 1 < FIN / 32) __syncthreads();
    }
    int rsub = (lane >> 4) * 4, csub = lane & 15;
#pragma unroll
    for (int rt = 0; rt < 2; rt++)
#pragma unroll
        for (int ct = 0; ct < 4; ct++) {
            int col = wn * 64 + ct * 16 + csub;
            int r0 = bm + wm * 32 + rt * 16 + rsub;
#pragma unroll
            for (int reg = 0; reg < 4; reg++) {
                int row = r0 + reg;
                if (row < M) {
                    float o = fmaxf(acc[rt][ct][reg] + bias[col], 0.f);
                    C[(size_t)(col >> 7) * ((size_t)M * 128) + (size_t)row * 128 + (col & 127)] = o;
                }
            }
        }
}

// ---------------- chunked propagate: writes z pre-split/pre-tiled for the GEMM ----------------
// zT layout (shorts): [blk][kt_local 0..7][hi|lo][2048]  — exact LDS image per K-slab.
__global__ __launch_bounds__(256) void k_prop(
    const float* __restrict__ hc, const float* __restrict__ x0c,
    const int* __restrict__ row_ptr, const int* __restrict__ src_sorted,
    const float* __restrict__ norm_sorted, const float* __restrict__ dinv,
    short* __restrict__ zT, int M, int chunk) {
    int wid = threadIdx.x >> 6, lane = threadIdx.x & 63;
    int node = blockIdx.x * 4 + wid;
    if (node >= M) return;
    int slot = lane >> 5, f4 = (lane & 31) * 4;
    int e0 = __builtin_amdgcn_readfirstlane(row_ptr[node]);
    int e1 = __builtin_amdgcn_readfirstlane(row_ptr[node + 1]);
    f32x4 acc = {0.f, 0.f, 0.f, 0.f};
    int e = e0 + slot;
    for (; e + 2 < e1; e += 4) {
        int s0 = src_sorted[e];     float w0 = norm_sorted[e];
        int s1 = src_sorted[e + 2]; float w1 = norm_sorted[e + 2];
        f32x4 v0 = *(const f32x4*)&hc[(size_t)s0 * 128 + f4];
        f32x4 v1 = *(const f32x4*)&hc[(size_t)s1 * 128 + f4];
        acc += w0 * v0 + w1 * v1;
    }
    if (e < e1) {
        int s0 = src_sorted[e]; float w0 = norm_sorted[e];
        acc += w0 * (*(const f32x4*)&hc[(size_t)s0 * 128 + f4]);
    }
#pragma unroll
    for (int c = 0; c < 4; c++) acc[c] += __shfl_xor(acc[c], 32);
    float di = dinv[node], sw = di * di;
    size_t base = (size_t)node * 128 + f4;
    f32x4 hrow = *(const f32x4*)&hc[base];
    f32x4 xv = *(const f32x4*)&x0c[base];
    f32x4 z = 0.9f * (acc + sw * hrow) + 0.1f * xv;
    if (slot == 0) {
        s16x4 zh, zl;
        { short h, l; split_bf16(z.x, h, l); zh[0] = h; zl[0] = l; }
        { short h, l; split_bf16(z.y, h, l); zh[1] = h; zl[1] = l; }
        { short h, l; split_bf16(z.z, h, l); zh[2] = h; zl[2] = l; }
        { short h, l; split_bf16(z.w, h, l); zh[3] = h; zl[3] = l; }
        int kt_loc = ((chunk << 7) + f4) >> 5;
        int g = (f4 >> 3) & 3;
        int j = f4 & 7;
        int rl = node & 63, blk = node >> 6;
        int cphys = ((rl & 15) ^ ((g & 1) << 2)) + 16 * g + 64 * (rl >> 4);
        size_t zi = ((size_t)(blk * 8 + kt_loc) * 2) * 2048 + (size_t)cphys * 8 + j;
        *(s16x4*)&zT[zi] = zh;
        *(s16x4*)&zT[zi + 2048] = zl;
    }
}

// ---------------- GEMM over pre-split/tiled z: h_next = relu(z @ W') ----------------
__global__ __launch_bounds__(512, 4) void k_mgemm_z(
    const short* __restrict__ zT, const short* __restrict__ Whi, const short* __restrict__ Wlo,
    float* __restrict__ C, int M, int rowmajor) {
    __shared__ short As_hi[2][2048];
    __shared__ short As_lo[2][2048];
    int tid = threadIdx.x, lane = tid & 63, wid = tid >> 6;
    int wm = wid >> 2, wn = wid & 3;
    int blk = blockIdx.x;
    int bm = blk * 64;
    size_t CS = (size_t)M * 128;
    int fr_g = lane >> 4, fr_r = lane & 15;
    int fr_base = (fr_r ^ ((fr_g & 1) << 2)) + 16 * fr_g;
    int c0 = (fr_base + 64 * (wm * 2 + 0)) * 8;
    int c1 = (fr_base + 64 * (wm * 2 + 1)) * 8;
    int lane_off = fr_g * 16 + fr_r;
    f32x4 acc[2][4] = {};
    auto img = [&](int kt) { return zT + ((size_t)(blk * 8 + kt) * 2) * 2048; };
    s16x8 vh = {}, vl = {}, nh = {}, nl = {};
    if (tid < 256) {
        const short* pi = img(0);
        vh = *(const s16x8*)&pi[tid * 8];
        vl = *(const s16x8*)&pi[2048 + tid * 8];
    }
    for (int kt = 0; kt < 8; kt++) {
        int buf = kt & 1;
        if (tid < 256) {
            *(s16x8*)&As_hi[buf][tid * 8] = vh;
            *(s16x8*)&As_lo[buf][tid * 8] = vl;
            if (kt + 1 < 8) {
                const short* pi = img(kt + 1);
                nh = *(const s16x8*)&pi[tid * 8];
                nl = *(const s16x8*)&pi[2048 + tid * 8];
            }
        }
        __syncthreads();
        s16x8 ah0 = *(const s16x8*)&As_hi[buf][c0], al0 = *(const s16x8*)&As_lo[buf][c0];
        s16x8 ah1 = *(const s16x8*)&As_hi[buf][c1], al1 = *(const s16x8*)&As_lo[buf][c1];
        size_t btile = (size_t)kt * 1024 + (size_t)(wn * 4) * 64;
#pragma unroll
        for (int ct = 0; ct < 4; ct++) {
            s16x8 bh = *(const s16x8*)&Whi[(btile + ct * 64 + lane_off) * 8];
            s16x8 bl = *(const s16x8*)&Wlo[(btile + ct * 64 + lane_off) * 8];
            acc[0][ct] = __builtin_amdgcn_mfma_f32_16x16x32_bf16(ah0, bh, acc[0][ct], 0, 0, 0);
            acc[0][ct] = __builtin_amdgcn_mfma_f32_16x16x32_bf16(al0, bh, acc[0][ct], 0, 0, 0);
            acc[0][ct] = __builtin_amdgcn_mfma_f32_16x16x32_bf16(ah0, bl, acc[0][ct], 0, 0, 0);
            acc[1][ct] = __builtin_amdgcn_mfma_f32_16x16x32_bf16(ah1, bh, acc[1][ct], 0, 0, 0);
            acc[1][ct] = __builtin_amdgcn_mfma_f32_16x16x32_bf16(al1, bh, acc[1][ct], 0, 0, 0);
            acc[1][ct] = __builtin_amdgcn_mfma_f32_16x16x32_bf16(ah1, bl, acc[1][ct], 0, 0, 0);
        }
        vh = nh; vl = nl;
        if (kt + 1 < 8) __syncthreads();
    }
    int rsub = (lane >> 4) * 4, csub = lane & 15;
#pragma unroll
    for (int rt = 0; rt < 2; rt++)
#pragma unroll
        for (int ct = 0; ct < 4; ct++) {
            int col = wn * 64 + ct * 16 + csub;
            int r0 = bm + wm * 32 + rt * 16 + rsub;
#pragma unroll
            for (int reg = 0; reg < 4; reg++) {
                int row = r0 + reg;
                if (row < M) {
                    float o = fmaxf(acc[rt][ct][reg], 0.f);
                    if (rowmajor) C[(size_t)row * HH + col] = o;
                    else C[(size_t)(col >> 7) * CS + (size_t)row * 128 + (col & 127)] = o;
                }
            }
        }
}

// ---------------- final: fp32 tiled logits GEMM + in-LDS softmax/argmax ----------------
__global__ __launch_bounds__(256) void k_final2(
    const float* __restrict__ h, const float* __restrict__ Wc, const float* __restrict__ bc,
    float* __restrict__ logits, float* __restrict__ soft, float* __restrict__ hard, int M) {
    __shared__ float As[16][64];
    __shared__ float Bs[16][64];
    __shared__ float lg[64][64];
    int tid = threadIdx.x;
    int tx = tid & 15, ty = tid >> 4;
    int bm = blockIdx.x * 64;
    int lm = tid >> 2, lk = (tid & 3) * 4;
    int lkb = tid >> 4, lnb = (tid & 15) * 4;
    bool arow_ok = (bm + lm) < M;
    float acc[4][4] = {};
    for (int k0 = 0; k0 < HH; k0 += 16) {
        float4 av = make_float4(0.f, 0.f, 0.f, 0.f);
        if (arow_ok) av = *(const float4*)&h[(size_t)(bm + lm) * HH + k0 + lk];
        As[lk + 0][lm] = av.x; As[lk + 1][lm] = av.y; As[lk + 2][lm] = av.z; As[lk + 3][lm] = av.w;
        *(float4*)&Bs[lkb][lnb] = *(const float4*)&Wc[(size_t)(k0 + lkb) * FOUT + lnb];
        __syncthreads();
#pragma unroll
        for (int k = 0; k < 16; k++) {
            float4 a = *(const float4*)&As[k][ty * 4];
            float4 b = *(const float4*)&Bs[k][tx * 4];
            acc[0][0] += a.x * b.x; acc[0][1] += a.x * b.y; acc[0][2] += a.x * b.z; acc[0][3] += a.x * b.w;
            acc[1][0] += a.y * b.x; acc[1][1] += a.y * b.y; acc[1][2] += a.y * b.z; acc[1][3] += a.y * b.w;
            acc[2][0] += a.z * b.x; acc[2][1] += a.z * b.y; acc[2][2] += a.z * b.z; acc[2][3] += a.z * b.w;
            acc[3][0] += a.w * b.x; acc[3][1] += a.w * b.y; acc[3][2] += a.w * b.z; acc[3][3] += a.w * b.w;
        }
        __syncthreads();
    }
#pragma unroll
    for (int i = 0; i < 4; i++)
        *(float4*)&lg[ty * 4 + i][tx * 4] = make_float4(acc[i][0], acc[i][1], acc[i][2], acc[i][3]);
    __syncthreads();

    int wid = tid >> 6, lane = tid & 63;
    float bv = bc[lane];
    for (int r = wid * 16; r < wid * 16 + 16; r++) {
        int node = bm + r;
        if (node >= M) continue;
        float v = lg[r][lane] + bv;
        float m = v;
        for (int off = 32; off > 0; off >>= 1) m = fmaxf(m, __shfl_xor(m, off));
        float ev = expf(v - m);
        float s = ev;
        for (int off = 32; off > 0; off >>= 1) s += __shfl_xor(s, off);
        float sm = ev / s;
        int idx = lane; float vv = v;
        for (int off = 1; off < 64; off <<= 1) {
            float ov = __shfl_xor(vv, off);
            int oi = __shfl_xor(idx, off);
            if (ov > vv || (ov == vv && oi < idx)) { vv = ov; idx = oi; }
        }
        logits[(size_t)node * FOUT + lane] = v;
        soft[(size_t)node * FOUT + lane] = sm;
        if (lane == 0) hard[node] = (float)idx;
    }
}

extern "C" void kernel_launch(void* const* d_in, const int* in_sizes, int n_in,
                              void* d_out, int out_size, void* d_ws, size_t ws_size,
                              hipStream_t stream) {
    const float* x  = (const float*)d_in[0];
    const int*   ei = (const int*)d_in[1];
    const float* W0 = (const float*)d_in[2];
    const float* b0 = (const float*)d_in[3];
    const float* Ws = (const float*)d_in[4];
    const float* Wc = (const float*)d_in[5];
    const float* bc = (const float*)d_in[6];
    const int E = in_sizes[1] / 2;
    const int N = in_sizes[0] / FIN;
    const int L = in_sizes[4] / (HH * HH);

    float* out    = (float*)d_out;
    float* logits = out;
    float* emb    = out + (size_t)N * FOUT;   // final h (row-major); chunked h pong for odd layers
    float* soft   = emb + (size_t)N * HH;
    float* hard   = soft + (size_t)N * FOUT;

    const int nblk = (N + 63) / 64;

    char* p = (char*)d_ws;
    size_t off = 0;
    auto alloc = [&](size_t bytes) { void* r = p + off; off += (bytes + 255) & ~(size_t)255; return r; };
    int*   cnt         = (int*)alloc((size_t)N * 4);
    int*   row_ptr     = (int*)alloc((size_t)(N + 1) * 4);
    int*   cur         = (int*)alloc((size_t)N * 4);
    int*   partial     = (int*)alloc(4096 * 4);
    float* dinv        = (float*)alloc((size_t)N * 4);
    int*   src_sorted  = (int*)alloc((size_t)E * 4);
    float* norm_sorted = (float*)alloc((size_t)E * 4);
    float* X0c         = (float*)alloc((size_t)N * HH * 4);        // chunked [2][N][128]
    float* hAc         = (float*)alloc((size_t)N * HH * 4);        // chunked ping
    short* zT          = (short*)alloc((size_t)nblk * 8 * 2 * 2048 * 2);  // pre-split/tiled z
    short* W0hi        = (short*)alloc((size_t)FIN * HH * 2);
    short* W0lo        = (short*)alloc((size_t)FIN * HH * 2);
    short* Wshi        = (short*)alloc((size_t)L * HH * HH * 2);
    short* Wslo        = (short*)alloc((size_t)L * HH * HH * 2);

    const int* srcp = ei;
    const int* dstp = ei + E;
    const size_t CS = (size_t)N * 128;

    hipMemsetAsync(cnt, 0, (size_t)N * 4, stream);
    k_count<<<(E + 255) / 256, 256, 0, stream>>>(dstp, cnt, E);
    const int nb = (N + 1023) / 1024;
    k_block_sums<<<nb, 256, 0, stream>>>(cnt, partial, N);
    k_scan_partials<<<1, 64, 0, stream>>>(partial, nb, row_ptr, N);
    k_write_rowptr<<<nb, 256, 0, stream>>>(cnt, partial, row_ptr, cur, dinv, N);
    k_scatter<<<(E + 255) / 256, 256, 0, stream>>>(srcp, dstp, dinv, cur, src_sorted, norm_sorted, E);

    k_wprep<<<(FIN * HH / 8 + 255) / 256, 256, 0, stream>>>(W0, W0hi, W0lo, FIN);
    k_wprep_all<<<(L * HH * HH / 8 + 255) / 256, 256, 0, stream>>>(Ws, Wshi, Wslo, L);

    const int npb = (N + 3) / 4;
    k_gemm0<<<nblk, 512, 0, stream>>>(x, W0hi, W0lo, b0, X0c, N);

    const float* hsrc = X0c;
    for (int i = 0; i < L; i++) {
        int last = (i == L - 1);
        // ping-pong: even layers -> hAc, odd layers -> emb region (chunked);
        // last layer overwrites emb row-major (after reading hsrc = hAc).
        float* hdst = last ? emb : ((i & 1) ? emb : hAc);
        for (int c = 0; c < 2; c++)
            k_prop<<<npb, 256, 0, stream>>>(hsrc + c * CS, X0c + c * CS, row_ptr,
                                            src_sorted, norm_sorted, dinv, zT, N, c);
        k_mgemm_z<<<nblk, 512, 0, stream>>>(zT, Wshi + (size_t)i * HH * HH, Wslo + (size_t)i * HH * HH,
                                            hdst, N, last);
        hsrc = hdst;
    }
    k_final2<<<nblk, 256, 0, stream>>>(emb, Wc, bc, logits, soft, hard, N);
}

// Round 15
// 4836.456 us; speedup vs baseline: 1.0251x; 1.0251x over previous
//
#include <hip/hip_runtime.h>
#include <hip/hip_bf16.h>
#include <math.h>

#define NN   100000
#define FIN  512
#define HH   256
#define FOUT 64

typedef __attribute__((ext_vector_type(8))) short s16x8;
typedef __attribute__((ext_vector_type(4))) float f32x4;

// ---------------- CSR build ----------------
__global__ void k_count(const int* __restrict__ dst, int* __restrict__ cnt, int E) {
    int i = blockIdx.x * 256 + threadIdx.x;
    if (i < E) atomicAdd(&cnt[dst[i]], 1);
}

__global__ void k_block_sums(const int* __restrict__ cnt, int* __restrict__ partial, int n) {
    __shared__ int red[256];
    int base = blockIdx.x * 1024;
    int t = threadIdx.x;
    int s = 0;
#pragma unroll
    for (int i = 0; i < 4; i++) { int idx = base + t * 4 + i; if (idx < n) s += cnt[idx]; }
    red[t] = s; __syncthreads();
    for (int off = 128; off > 0; off >>= 1) {
        if (t < off) red[t] += red[t + off];
        __syncthreads();
    }
    if (t == 0) partial[blockIdx.x] = red[0];
}

__global__ void k_scan_partials(int* partial, int nb, int* row_ptr, int n) {
    if (threadIdx.x == 0) {
        int run = 0;
        for (int i = 0; i < nb; i++) { int v = partial[i]; partial[i] = run; run += v; }
        row_ptr[n] = run;
    }
}

// also computes dinv (fused, saves a launch)
__global__ void k_write_rowptr(const int* __restrict__ cnt, const int* __restrict__ partial,
                               int* __restrict__ row_ptr, int* __restrict__ cur,
                               float* __restrict__ dinv, int n) {
    __shared__ int sc[256];
    int base = blockIdx.x * 1024;
    int t = threadIdx.x;
    int v[4]; int s = 0;
#pragma unroll
    for (int i = 0; i < 4; i++) { int idx = base + t * 4 + i; v[i] = (idx < n) ? cnt[idx] : 0; s += v[i]; }
    sc[t] = s; __syncthreads();
    for (int off = 1; off < 256; off <<= 1) {
        int add = (t >= off) ? sc[t - off] : 0;
        __syncthreads();
        sc[t] += add;
        __syncthreads();
    }
    int run = partial[blockIdx.x] + sc[t] - s;
#pragma unroll
    for (int i = 0; i < 4; i++) {
        int idx = base + t * 4 + i;
        if (idx < n) {
            row_ptr[idx] = run; cur[idx] = run; run += v[i];
            dinv[idx] = 1.0f / sqrtf((float)(v[i] + 1));
        }
    }
}

__global__ void k_scatter(const int* __restrict__ src, const int* __restrict__ dst,
                          const float* __restrict__ dinv, int* __restrict__ cur,
                          int* __restrict__ src_sorted, float* __restrict__ norm_sorted, int E) {
    int i = blockIdx.x * 256 + threadIdx.x;
    if (i < E) {
        int s = src[i], d = dst[i];
        int p = atomicAdd(&cur[d], 1);
        src_sorted[p] = s;
        norm_sorted[p] = dinv[s] * dinv[d];
    }
}

// ---------------- bf16 split helpers ----------------
__device__ __forceinline__ short f2bf_rn(float f) {
    unsigned b = __float_as_uint(f);
    unsigned r = b + 0x7FFFu + ((b >> 16) & 1u);
    return (short)(r >> 16);
}
__device__ __forceinline__ float bf2f(short h) {
    return __uint_as_float(((unsigned)(unsigned short)h) << 16);
}
__device__ __forceinline__ void split_bf16(float f, short& hi, short& lo) {
    hi = f2bf_rn(f);
    lo = f2bf_rn(f - bf2f(hi));
}

// ---------------- weight prep: W0 (scale=1, no diag) ----------------
__global__ void k_wprep(const float* __restrict__ W, short* __restrict__ whi,
                        short* __restrict__ wlo, int K) {
    int t = blockIdx.x * 256 + threadIdx.x;
    int total = K * HH / 8;
    if (t >= total) return;
    int colin = t & 15, g = (t >> 4) & 3, nt = (t >> 6) & 15, kt = t >> 10;
    int col = nt * 16 + colin, kb = kt * 32 + g * 8;
    s16x8 h8, l8;
#pragma unroll
    for (int j = 0; j < 8; j++) {
        float f = W[(size_t)(kb + j) * HH + col];
        short h, l; split_bf16(f, h, l);
        h8[j] = h; l8[j] = l;
    }
    *(s16x8*)&whi[(size_t)t * 8] = h8;
    *(s16x8*)&wlo[(size_t)t * 8] = l8;
}

// ---------------- batched weight prep for all layers: W' = beta*Ws + (1-beta)*I ----------------
__global__ void k_wprep_all(const float* __restrict__ Ws, short* __restrict__ whi,
                            short* __restrict__ wlo, int L) {
    int t = blockIdx.x * 256 + threadIdx.x;
    const int per = HH * HH / 8;   // 8192 chunks per layer
    if (t >= L * per) return;
    int layer = t / per;
    int tl = t - layer * per;
    float beta = (float)log(0.5 / (layer + 1) + 1.0);
    const float* W = Ws + (size_t)layer * HH * HH;
    int colin = tl & 15, g = (tl >> 4) & 3, nt = (tl >> 6) & 15, kt = tl >> 10;
    int col = nt * 16 + colin, kb = kt * 32 + g * 8;
    s16x8 h8, l8;
#pragma unroll
    for (int j = 0; j < 8; j++) {
        float f = beta * W[(size_t)(kb + j) * HH + col];
        if ((kb + j) == col) f += 1.0f - beta;
        short h, l; split_bf16(f, h, l);
        h8[j] = h; l8[j] = l;
    }
    *(s16x8*)&whi[(size_t)t * 8] = h8;
    *(s16x8*)&wlo[(size_t)t * 8] = l8;
}

// ---------------- first GEMM: X0 = relu(x@W0 + b0), 8-wave blocks, chunked out ----------------
__global__ __launch_bounds__(512, 4) void k_gemm0(
    const float* __restrict__ A, const short* __restrict__ Whi, const short* __restrict__ Wlo,
    const float* __restrict__ bias, float* __restrict__ C, int M) {
    __shared__ short As_hi[2][2048];
    __shared__ short As_lo[2][2048];
    int tid = threadIdx.x, lane = tid & 63, wid = tid >> 6;
    int wm = wid >> 2, wn = wid & 3;            // 2 row-groups x 4 col-groups
    int bm = blockIdx.x * 64;
    int st_row = tid >> 2, st_g = tid & 3;      // staging: tid<256 only
    int st_cphys = ((st_row & 15) ^ ((st_g & 1) << 2)) + 16 * st_g + 64 * (st_row >> 4);
    const float* st_ap = A + (size_t)(bm + st_row) * FIN + st_g * 8;
    bool st_ok = (tid < 256) && (bm + st_row) < M;
    int fr_g = lane >> 4, fr_r = lane & 15;
    int fr_base = (fr_r ^ ((fr_g & 1) << 2)) + 16 * fr_g;
    int c0 = (fr_base + 64 * (wm * 2 + 0)) * 8;
    int c1 = (fr_base + 64 * (wm * 2 + 1)) * 8;
    int lane_off = fr_g * 16 + fr_r;
    f32x4 acc[2][4] = {};
    f32x4 v0 = {0.f, 0.f, 0.f, 0.f}, v1 = v0, n0 = v0, n1 = v0;
    if (st_ok) { v0 = *(const f32x4*)(st_ap); v1 = *(const f32x4*)(st_ap + 4); }
    for (int kt = 0; kt < FIN / 32; kt++) {
        int buf = kt & 1;
        if (tid < 256) {
            s16x8 h8, l8;
            float fv[8] = {v0.x, v0.y, v0.z, v0.w, v1.x, v1.y, v1.z, v1.w};
#pragma unroll
            for (int j = 0; j < 8; j++) { short hh, ll; split_bf16(fv[j], hh, ll); h8[j] = hh; l8[j] = ll; }
            *(s16x8*)&As_hi[buf][st_cphys * 8] = h8;
            *(s16x8*)&As_lo[buf][st_cphys * 8] = l8;
            if (kt + 1 < FIN / 32 && st_ok) {
                int k0n = (kt + 1) * 32;
                n0 = *(const f32x4*)(st_ap + k0n);
                n1 = *(const f32x4*)(st_ap + k0n + 4);
            }
        }
        __syncthreads();
        s16x8 ah0 = *(const s16x8*)&As_hi[buf][c0], al0 = *(const s16x8*)&As_lo[buf][c0];
        s16x8 ah1 = *(const s16x8*)&As_hi[buf][c1], al1 = *(const s16x8*)&As_lo[buf][c1];
        size_t btile = (size_t)kt * 1024 + (size_t)(wn * 4) * 64;
#pragma unroll
        for (int ct = 0; ct < 4; ct++) {
            s16x8 bh = *(const s16x8*)&Whi[(btile + ct * 64 + lane_off) * 8];
            s16x8 bl = *(const s16x8*)&Wlo[(btile + ct * 64 + lane_off) * 8];
            acc[0][ct] = __builtin_amdgcn_mfma_f32_16x16x32_bf16(ah0, bh, acc[0][ct], 0, 0, 0);
            acc[0][ct] = __builtin_amdgcn_mfma_f32_16x16x32_bf16(al0, bh, acc[0][ct], 0, 0, 0);
            acc[0][ct] = __builtin_amdgcn_mfma_f32_16x16x32_bf16(ah0, bl, acc[0][ct], 0, 0, 0);
            acc[1][ct] = __builtin_amdgcn_mfma_f32_16x16x32_bf16(ah1, bh, acc[1][ct], 0, 0, 0);
            acc[1][ct] = __builtin_amdgcn_mfma_f32_16x16x32_bf16(al1, bh, acc[1][ct], 0, 0, 0);
            acc[1][ct] = __builtin_amdgcn_mfma_f32_16x16x32_bf16(ah1, bl, acc[1][ct], 0, 0, 0);
        }
        v0 = n0; v1 = n1;
        if (kt + 1 < FIN / 32) __syncthreads();
    }
    int rsub = (lane >> 4) * 4, csub = lane & 15;
#pragma unroll
    for (int rt = 0; rt < 2; rt++)
#pragma unroll
        for (int ct = 0; ct < 4; ct++) {
            int col = wn * 64 + ct * 16 + csub;
            int r0 = bm + wm * 32 + rt * 16 + rsub;
#pragma unroll
            for (int reg = 0; reg < 4; reg++) {
                int row = r0 + reg;
                if (row < M) {
                    float o = fmaxf(acc[rt][ct][reg] + bias[col], 0.f);
                    C[(size_t)(col >> 7) * ((size_t)M * 128) + (size_t)row * 128 + (col & 127)] = o;
                }
            }
        }
}

// ---------------- chunked propagate: one 128-feature chunk per launch ----------------
__global__ __launch_bounds__(256) void k_prop(
    const float* __restrict__ hc, const float* __restrict__ x0c,
    const int* __restrict__ row_ptr, const int* __restrict__ src_sorted,
    const float* __restrict__ norm_sorted, const float* __restrict__ dinv,
    float* __restrict__ zc, int M) {
    int wid = threadIdx.x >> 6, lane = threadIdx.x & 63;
    int node = blockIdx.x * 4 + wid;
    if (node >= M) return;
    int slot = lane >> 5, f4 = (lane & 31) * 4;
    int e0 = __builtin_amdgcn_readfirstlane(row_ptr[node]);
    int e1 = __builtin_amdgcn_readfirstlane(row_ptr[node + 1]);
    f32x4 acc = {0.f, 0.f, 0.f, 0.f};
    int e = e0 + slot;
    for (; e + 2 < e1; e += 4) {
        int s0 = src_sorted[e];     float w0 = norm_sorted[e];
        int s1 = src_sorted[e + 2]; float w1 = norm_sorted[e + 2];
        f32x4 v0 = *(const f32x4*)&hc[(size_t)s0 * 128 + f4];
        f32x4 v1 = *(const f32x4*)&hc[(size_t)s1 * 128 + f4];
        acc += w0 * v0 + w1 * v1;
    }
    if (e < e1) {
        int s0 = src_sorted[e]; float w0 = norm_sorted[e];
        acc += w0 * (*(const f32x4*)&hc[(size_t)s0 * 128 + f4]);
    }
#pragma unroll
    for (int c = 0; c < 4; c++) acc[c] += __shfl_xor(acc[c], 32);
    float di = dinv[node], sw = di * di;
    size_t base = (size_t)node * 128 + f4;
    f32x4 hrow = *(const f32x4*)&hc[base];
    f32x4 xv = *(const f32x4*)&x0c[base];
    f32x4 z = 0.9f * (acc + sw * hrow) + 0.1f * xv;
    if (slot == 0) *(f32x4*)&zc[base] = z;
}

// ---------------- GEMM over chunked z: h_next = relu(z @ W'), 8-wave blocks ----------------
__global__ __launch_bounds__(512, 4) void k_mgemm_z(
    const float* __restrict__ Zc, const short* __restrict__ Whi, const short* __restrict__ Wlo,
    float* __restrict__ C, int M, int rowmajor) {
    __shared__ short As_hi[2][2048];
    __shared__ short As_lo[2][2048];
    int tid = threadIdx.x, lane = tid & 63, wid = tid >> 6;
    int wm = wid >> 2, wn = wid & 3;
    int bm = blockIdx.x * 64;
    size_t CS = (size_t)M * 128;
    int st_row = tid >> 2, st_g = tid & 3;
    bool st_ok = (tid < 256) && (bm + st_row) < M;
    int st_cphys = ((st_row & 15) ^ ((st_g & 1) << 2)) + 16 * st_g + 64 * (st_row >> 4);
    int fr_g = lane >> 4, fr_r = lane & 15;
    int fr_base = (fr_r ^ ((fr_g & 1) << 2)) + 16 * fr_g;
    int c0 = (fr_base + 64 * (wm * 2 + 0)) * 8;
    int c1 = (fr_base + 64 * (wm * 2 + 1)) * 8;
    int lane_off = fr_g * 16 + fr_r;
    f32x4 acc[2][4] = {};
    auto zslab = [&](int kt) {
        int k0 = kt * 32;
        return Zc + (size_t)(k0 >> 7) * CS + (size_t)(bm + st_row) * 128 + (k0 & 127) + st_g * 8;
    };
    f32x4 v0 = {0.f, 0.f, 0.f, 0.f}, v1 = v0, n0 = v0, n1 = v0;
    if (st_ok) { const float* zp = zslab(0); v0 = *(const f32x4*)zp; v1 = *(const f32x4*)(zp + 4); }
    for (int kt = 0; kt < 8; kt++) {
        int buf = kt & 1;
        if (tid < 256) {
            s16x8 h8, l8;
            float fv[8] = {v0.x, v0.y, v0.z, v0.w, v1.x, v1.y, v1.z, v1.w};
#pragma unroll
            for (int j = 0; j < 8; j++) { short hh, ll; split_bf16(fv[j], hh, ll); h8[j] = hh; l8[j] = ll; }
            *(s16x8*)&As_hi[buf][st_cphys * 8] = h8;
            *(s16x8*)&As_lo[buf][st_cphys * 8] = l8;
            if (kt + 1 < 8 && st_ok) {
                const float* zp = zslab(kt + 1);
                n0 = *(const f32x4*)zp; n1 = *(const f32x4*)(zp + 4);
            }
        }
        __syncthreads();
        s16x8 ah0 = *(const s16x8*)&As_hi[buf][c0], al0 = *(const s16x8*)&As_lo[buf][c0];
        s16x8 ah1 = *(const s16x8*)&As_hi[buf][c1], al1 = *(const s16x8*)&As_lo[buf][c1];
        size_t btile = (size_t)kt * 1024 + (size_t)(wn * 4) * 64;
#pragma unroll
        for (int ct = 0; ct < 4; ct++) {
            s16x8 bh = *(const s16x8*)&Whi[(btile + ct * 64 + lane_off) * 8];
            s16x8 bl = *(const s16x8*)&Wlo[(btile + ct * 64 + lane_off) * 8];
            acc[0][ct] = __builtin_amdgcn_mfma_f32_16x16x32_bf16(ah0, bh, acc[0][ct], 0, 0, 0);
            acc[0][ct] = __builtin_amdgcn_mfma_f32_16x16x32_bf16(al0, bh, acc[0][ct], 0, 0, 0);
            acc[0][ct] = __builtin_amdgcn_mfma_f32_16x16x32_bf16(ah0, bl, acc[0][ct], 0, 0, 0);
            acc[1][ct] = __builtin_amdgcn_mfma_f32_16x16x32_bf16(ah1, bh, acc[1][ct], 0, 0, 0);
            acc[1][ct] = __builtin_amdgcn_mfma_f32_16x16x32_bf16(al1, bh, acc[1][ct], 0, 0, 0);
            acc[1][ct] = __builtin_amdgcn_mfma_f32_16x16x32_bf16(ah1, bl, acc[1][ct], 0, 0, 0);
        }
        v0 = n0; v1 = n1;
        if (kt + 1 < 8) __syncthreads();
    }
    int rsub = (lane >> 4) * 4, csub = lane & 15;
#pragma unroll
    for (int rt = 0; rt < 2; rt++)
#pragma unroll
        for (int ct = 0; ct < 4; ct++) {
            int col = wn * 64 + ct * 16 + csub;
            int r0 = bm + wm * 32 + rt * 16 + rsub;
#pragma unroll
            for (int reg = 0; reg < 4; reg++) {
                int row = r0 + reg;
                if (row < M) {
                    float o = fmaxf(acc[rt][ct][reg], 0.f);
                    if (rowmajor) C[(size_t)row * HH + col] = o;
                    else C[(size_t)(col >> 7) * CS + (size_t)row * 128 + (col & 127)] = o;
                }
            }
        }
}

// ---------------- final: fp32 tiled logits GEMM + in-LDS softmax/argmax ----------------
__global__ __launch_bounds__(256) void k_final2(
    const float* __restrict__ h, const float* __restrict__ Wc, const float* __restrict__ bc,
    float* __restrict__ logits, float* __restrict__ soft, float* __restrict__ hard, int M) {
    __shared__ float As[16][64];
    __shared__ float Bs[16][64];
    __shared__ float lg[64][64];
    int tid = threadIdx.x;
    int tx = tid & 15, ty = tid >> 4;
    int bm = blockIdx.x * 64;
    int lm = tid >> 2, lk = (tid & 3) * 4;
    int lkb = tid >> 4, lnb = (tid & 15) * 4;
    bool arow_ok = (bm + lm) < M;
    float acc[4][4] = {};
    for (int k0 = 0; k0 < HH; k0 += 16) {
        float4 av = make_float4(0.f, 0.f, 0.f, 0.f);
        if (arow_ok) av = *(const float4*)&h[(size_t)(bm + lm) * HH + k0 + lk];
        As[lk + 0][lm] = av.x; As[lk + 1][lm] = av.y; As[lk + 2][lm] = av.z; As[lk + 3][lm] = av.w;
        *(float4*)&Bs[lkb][lnb] = *(const float4*)&Wc[(size_t)(k0 + lkb) * FOUT + lnb];
        __syncthreads();
#pragma unroll
        for (int k = 0; k < 16; k++) {
            float4 a = *(const float4*)&As[k][ty * 4];
            float4 b = *(const float4*)&Bs[k][tx * 4];
            acc[0][0] += a.x * b.x; acc[0][1] += a.x * b.y; acc[0][2] += a.x * b.z; acc[0][3] += a.x * b.w;
            acc[1][0] += a.y * b.x; acc[1][1] += a.y * b.y; acc[1][2] += a.y * b.z; acc[1][3] += a.y * b.w;
            acc[2][0] += a.z * b.x; acc[2][1] += a.z * b.y; acc[2][2] += a.z * b.z; acc[2][3] += a.z * b.w;
            acc[3][0] += a.w * b.x; acc[3][1] += a.w * b.y; acc[3][2] += a.w * b.z; acc[3][3] += a.w * b.w;
        }
        __syncthreads();
    }
#pragma unroll
    for (int i = 0; i < 4; i++)
        *(float4*)&lg[ty * 4 + i][tx * 4] = make_float4(acc[i][0], acc[i][1], acc[i][2], acc[i][3]);
    __syncthreads();

    int wid = tid >> 6, lane = tid & 63;
    float bv = bc[lane];
    for (int r = wid * 16; r < wid * 16 + 16; r++) {
        int node = bm + r;
        if (node >= M) continue;
        float v = lg[r][lane] + bv;
        float m = v;
        for (int off = 32; off > 0; off >>= 1) m = fmaxf(m, __shfl_xor(m, off));
        float ev = expf(v - m);
        float s = ev;
        for (int off = 32; off > 0; off >>= 1) s += __shfl_xor(s, off);
        float sm = ev / s;
        int idx = lane; float vv = v;
        for (int off = 1; off < 64; off <<= 1) {
            float ov = __shfl_xor(vv, off);
            int oi = __shfl_xor(idx, off);
            if (ov > vv || (ov == vv && oi < idx)) { vv = ov; idx = oi; }
        }
        logits[(size_t)node * FOUT + lane] = v;
        soft[(size_t)node * FOUT + lane] = sm;
        if (lane == 0) hard[node] = (float)idx;
    }
}

extern "C" void kernel_launch(void* const* d_in, const int* in_sizes, int n_in,
                              void* d_out, int out_size, void* d_ws, size_t ws_size,
                              hipStream_t stream) {
    const float* x  = (const float*)d_in[0];
    const int*   ei = (const int*)d_in[1];
    const float* W0 = (const float*)d_in[2];
    const float* b0 = (const float*)d_in[3];
    const float* Ws = (const float*)d_in[4];
    const float* Wc = (const float*)d_in[5];
    const float* bc = (const float*)d_in[6];
    const int E = in_sizes[1] / 2;
    const int N = in_sizes[0] / FIN;
    const int L = in_sizes[4] / (HH * HH);

    float* out    = (float*)d_out;
    float* logits = out;
    float* emb    = out + (size_t)N * FOUT;   // [N,256] row-major — final h
    float* soft   = emb + (size_t)N * HH;
    float* hard   = soft + (size_t)N * FOUT;

    char* p = (char*)d_ws;
    size_t off = 0;
    auto alloc = [&](size_t bytes) { void* r = p + off; off += (bytes + 255) & ~(size_t)255; return r; };
    int*   cnt         = (int*)alloc((size_t)N * 4);
    int*   row_ptr     = (int*)alloc((size_t)(N + 1) * 4);
    int*   cur         = (int*)alloc((size_t)N * 4);
    int*   partial     = (int*)alloc(4096 * 4);
    float* dinv        = (float*)alloc((size_t)N * 4);
    int*   src_sorted  = (int*)alloc((size_t)E * 4);
    float* norm_sorted = (float*)alloc((size_t)E * 4);
    float* X0c         = (float*)alloc((size_t)N * HH * 4);   // chunked [2][N][128]
    float* hAc         = (float*)alloc((size_t)N * HH * 4);   // chunked ping
    float* hBc         = (float*)alloc((size_t)N * HH * 4);   // chunked pong
    short* W0hi        = (short*)alloc((size_t)FIN * HH * 2);
    short* W0lo        = (short*)alloc((size_t)FIN * HH * 2);
    short* Wshi        = (short*)alloc((size_t)L * HH * HH * 2);
    short* Wslo        = (short*)alloc((size_t)L * HH * HH * 2);

    const int* srcp = ei;
    const int* dstp = ei + E;
    const size_t CS = (size_t)N * 128;

    hipMemsetAsync(cnt, 0, (size_t)N * 4, stream);
    k_count<<<(E + 255) / 256, 256, 0, stream>>>(dstp, cnt, E);
    const int nb = (N + 1023) / 1024;
    k_block_sums<<<nb, 256, 0, stream>>>(cnt, partial, N);
    k_scan_partials<<<1, 64, 0, stream>>>(partial, nb, row_ptr, N);
    k_write_rowptr<<<nb, 256, 0, stream>>>(cnt, partial, row_ptr, cur, dinv, N);
    k_scatter<<<(E + 255) / 256, 256, 0, stream>>>(srcp, dstp, dinv, cur, src_sorted, norm_sorted, E);

    k_wprep<<<(FIN * HH / 8 + 255) / 256, 256, 0, stream>>>(W0, W0hi, W0lo, FIN);
    k_wprep_all<<<(L * HH * HH / 8 + 255) / 256, 256, 0, stream>>>(Ws, Wshi, Wslo, L);

    const int nblk = (N + 63) / 64;
    const int npb  = (N + 3) / 4;
    k_gemm0<<<nblk, 512, 0, stream>>>(x, W0hi, W0lo, b0, X0c, N);

    const float* hsrc = X0c;
    for (int i = 0; i < L; i++) {
        int last = (i == L - 1);
        float* hdst = last ? emb : ((i & 1) ? hBc : hAc);
        float* zb = last ? hBc : hdst;   // z aliases hdst (chunked) except last layer
        for (int c = 0; c < 2; c++)
            k_prop<<<npb, 256, 0, stream>>>(hsrc + c * CS, X0c + c * CS, row_ptr,
                                            src_sorted, norm_sorted, dinv, zb + c * CS, N);
        k_mgemm_z<<<nblk, 512, 0, stream>>>(zb, Wshi + (size_t)i * HH * HH, Wslo + (size_t)i * HH * HH,
                                            hdst, N, last);
        hsrc = hdst;
    }
    k_final2<<<nblk, 256, 0, stream>>>(emb, Wc, bc, logits, soft, hard, N);
}